// Round 1
// baseline (6250.285 us; speedup 1.0000x reference)
//
#include <hip/hip_runtime.h>
#include <cstdint>
#include <cstddef>

// Problem constants
#define H_DIM   1024
#define T_STEPS 512           // L*N = 64*8 flattened time-major
#define VOCAB   32000
#define CSTR    16            // counter stride in ints (64B) to avoid line sharing
#define NBLK    128           // blocks per layer
#define SPIN_CAP 5000000      // hang guard

// ---------------------------------------------------------------------------
// init: zero h slot 0, zero counters (ws is poisoned 0xAA each launch), preset
// slot-0 counters to "ready", build time-major gather map xmap[t]=x[n,l].
// ---------------------------------------------------------------------------
__global__ void init_ws_k(const int* __restrict__ x,
                          float* __restrict__ h0h, float* __restrict__ h1h,
                          int* __restrict__ cnt0, int* __restrict__ cnt1,
                          int* __restrict__ xmap)
{
  int tid = blockIdx.x * blockDim.x + threadIdx.x;
  int nt  = gridDim.x * blockDim.x;
  for (int i = tid; i < H_DIM; i += nt) { h0h[i] = 0.f; h1h[i] = 0.f; }
  for (int i = tid; i < (T_STEPS + 1) * CSTR; i += nt) { cnt0[i] = 0; cnt1[i] = 0; }
  for (int t = tid; t < T_STEPS; t += nt) xmap[t] = x[(t & 7) * 64 + (t >> 3)];
  if (tid == 0) { cnt0[0] = NBLK; cnt1[0] = NBLK; }   // slot 0 = initial zeros, ready
}

// ---------------------------------------------------------------------------
// fp32 GEMM  C[M,N] = A[M,K] @ B[N,K]^T + bias0 + bias1.
// If A==null, row t of A is gathered as emb[xmap[t]].
// 128x128 tile, BK=16, 256 threads, 8x8 per-thread microtile.
// ---------------------------------------------------------------------------
#define BM 128
#define BN 128
#define BKD 16

__global__ __launch_bounds__(256) void gemm_atb_k(
    const float* __restrict__ A, const float* __restrict__ emb,
    const int* __restrict__ xmap,
    const float* __restrict__ B,
    const float* __restrict__ bias0, const float* __restrict__ bias1,
    float* __restrict__ C, int M, int N, int K)
{
  __shared__ __align__(16) float As[BKD][BM + 4];
  __shared__ __align__(16) float Bs[BKD][BN + 4];
  const int tid = threadIdx.x;
  const int tx = tid & 15, ty = tid >> 4;
  const int m0 = blockIdx.y * BM, n0 = blockIdx.x * BN;
  const int lr = tid >> 1;           // 0..127: row within tile
  const int lk = (tid & 1) * 8;      // 0 or 8: k sub-chunk
  const float* arow = A ? (A + (size_t)(m0 + lr) * K)
                        : (emb + (size_t)xmap[m0 + lr] * K);
  const float* brow = B + (size_t)(n0 + lr) * K;

  float acc[8][8];
  #pragma unroll
  for (int i = 0; i < 8; ++i)
    #pragma unroll
    for (int j = 0; j < 8; ++j) acc[i][j] = 0.f;

  for (int k0 = 0; k0 < K; k0 += BKD) {
    float4 a0 = *(const float4*)(arow + k0 + lk);
    float4 a1 = *(const float4*)(arow + k0 + lk + 4);
    float4 b0 = *(const float4*)(brow + k0 + lk);
    float4 b1 = *(const float4*)(brow + k0 + lk + 4);
    __syncthreads();   // protect previous iteration's LDS reads
    As[lk+0][lr]=a0.x; As[lk+1][lr]=a0.y; As[lk+2][lr]=a0.z; As[lk+3][lr]=a0.w;
    As[lk+4][lr]=a1.x; As[lk+5][lr]=a1.y; As[lk+6][lr]=a1.z; As[lk+7][lr]=a1.w;
    Bs[lk+0][lr]=b0.x; Bs[lk+1][lr]=b0.y; Bs[lk+2][lr]=b0.z; Bs[lk+3][lr]=b0.w;
    Bs[lk+4][lr]=b1.x; Bs[lk+5][lr]=b1.y; Bs[lk+6][lr]=b1.z; Bs[lk+7][lr]=b1.w;
    __syncthreads();
    #pragma unroll
    for (int kk = 0; kk < BKD; ++kk) {
      float4 av0 = *(const float4*)&As[kk][ty*8];
      float4 av1 = *(const float4*)&As[kk][ty*8+4];
      float4 bv0 = *(const float4*)&Bs[kk][tx*8];
      float4 bv1 = *(const float4*)&Bs[kk][tx*8+4];
      float av[8] = {av0.x,av0.y,av0.z,av0.w,av1.x,av1.y,av1.z,av1.w};
      float bv[8] = {bv0.x,bv0.y,bv0.z,bv0.w,bv1.x,bv1.y,bv1.z,bv1.w};
      #pragma unroll
      for (int i = 0; i < 8; ++i)
        #pragma unroll
        for (int j = 0; j < 8; ++j) acc[i][j] += av[i] * bv[j];
    }
  }
  float bvp[8];
  #pragma unroll
  for (int j = 0; j < 8; ++j) {
    int n = n0 + tx*8 + j;
    float s = 0.f;
    if (bias0) s += bias0[n];
    if (bias1) s += bias1[n];
    bvp[j] = s;
  }
  #pragma unroll
  for (int i = 0; i < 8; ++i) {
    int m = m0 + ty*8 + i;
    float* crow = C + (size_t)m * N + n0 + tx*8;
    float4 o0, o1;
    o0.x=acc[i][0]+bvp[0]; o0.y=acc[i][1]+bvp[1]; o0.z=acc[i][2]+bvp[2]; o0.w=acc[i][3]+bvp[3];
    o1.x=acc[i][4]+bvp[4]; o1.y=acc[i][5]+bvp[5]; o1.z=acc[i][6]+bvp[6]; o1.w=acc[i][7]+bvp[7];
    *(float4*)crow = o0;
    *(float4*)(crow + 4) = o1;
  }
}

// ---------------------------------------------------------------------------
// Persistent sequential LSTM scan. 256 blocks x 256 threads, 1 block/CU.
// Blocks 0..127: layer 0 (W_hh0 in regs; W_ih0 path precomputed into G0).
// Blocks 128..255: layer 1 ([W_ih1|W_hh1] in regs, K=2048), lags one step.
// Block b owns hidden units j in [8b, 8b+8) for all 4 gates + their c state.
// Sync: per-step counters (agent-scope atomics, write-through h stores).
// ---------------------------------------------------------------------------
__device__ __forceinline__ float sigmoid_f(float v) { return 1.f / (1.f + expf(-v)); }

__global__ __launch_bounds__(256, 1) void lstm_seq_k(
    const float* __restrict__ Whh0,
    const float* __restrict__ Wih1,
    const float* __restrict__ Whh1,
    const float* __restrict__ bih1,
    const float* __restrict__ bhh1,
    const float* __restrict__ G0,
    float* __restrict__ h0h, float* __restrict__ h1h,   // (T+1) x 1024 histories
    int* __restrict__ cnt0, int* __restrict__ cnt1,
    float* __restrict__ out_hc)                          // h(2x1024) then c(2x1024)
{
  const int Bid   = blockIdx.x;
  const int layer = Bid >> 7;
  const int b     = Bid & 127;
  const int jbase = b * 8;
  const int tid   = threadIdx.x;
  const int w     = tid >> 6;    // wave index == gate index (i,f,g,o)
  const int lane  = tid & 63;    // k-chunk index

  __shared__ __align__(16) float hbuf[2048];
  __shared__ float gbuf[4][8];
  __shared__ float cbuf[8];

  if (tid < 8) cbuf[tid] = 0.f;

  if (layer == 0) {
    // ---- layer 0: K=1024, 16 weights/row/lane, 8 rows -> 128 VGPRs ----
    float wr[8][16];
    #pragma unroll
    for (int j = 0; j < 8; ++j) {
      const float* p = Whh0 + (size_t)(w*1024 + jbase + j) * 1024 + lane*16;
      #pragma unroll
      for (int q = 0; q < 4; ++q) {
        float4 v = *(const float4*)(p + q*4);
        wr[j][q*4+0]=v.x; wr[j][q*4+1]=v.y; wr[j][q*4+2]=v.z; wr[j][q*4+3]=v.w;
      }
    }
    __syncthreads();
    for (int t = 0; t < T_STEPS; ++t) {
      if (tid == 0) {
        int sp = 0;
        while (__hip_atomic_load(&cnt0[t*CSTR], __ATOMIC_RELAXED, __HIP_MEMORY_SCOPE_AGENT) < NBLK) {
          __builtin_amdgcn_s_sleep(1);
          if (++sp > SPIN_CAP) break;
        }
      }
      __syncthreads();
      // issue G0 loads early so their latency hides under the matvec
      float g_i = 0.f, g_f = 0.f, g_g = 0.f, g_o = 0.f;
      if (tid < 8) {
        const float* g0 = G0 + (size_t)t*4096 + jbase + tid;
        g_i = g0[0]; g_f = g0[1024]; g_g = g0[2048]; g_o = g0[3072];
      }
      { // stage h_{t-1} (cache-bypassing loads -> LDS)
        const float* src = h0h + (size_t)t * 1024;
        #pragma unroll
        for (int q = 0; q < 4; ++q) {
          int idx = tid*4 + q;
          hbuf[idx] = __hip_atomic_load(const_cast<float*>(&src[idx]),
                                        __ATOMIC_RELAXED, __HIP_MEMORY_SCOPE_AGENT);
        }
      }
      __syncthreads();
      float acc[8];
      {
        float xv[16];
        const float* hv = &hbuf[lane*16];
        #pragma unroll
        for (int q = 0; q < 4; ++q) {
          float4 v = *(const float4*)(hv + q*4);
          xv[q*4+0]=v.x; xv[q*4+1]=v.y; xv[q*4+2]=v.z; xv[q*4+3]=v.w;
        }
        #pragma unroll
        for (int j = 0; j < 8; ++j) {
          float s = 0.f;
          #pragma unroll
          for (int q = 0; q < 16; ++q) s += wr[j][q] * xv[q];
          acc[j] = s;
        }
      }
      #pragma unroll
      for (int j = 0; j < 8; ++j)
        #pragma unroll
        for (int msk = 1; msk < 64; msk <<= 1)
          acc[j] += __shfl_xor(acc[j], msk, 64);
      if (lane == 0) {
        #pragma unroll
        for (int j = 0; j < 8; ++j) gbuf[w][j] = acc[j];
      }
      __syncthreads();
      if (tid < 8) {
        const int j = tid;
        float iv = sigmoid_f(gbuf[0][j] + g_i);
        float fv = sigmoid_f(gbuf[1][j] + g_f);
        float gv = tanhf   (gbuf[2][j] + g_g);
        float ov = sigmoid_f(gbuf[3][j] + g_o);
        float c  = fv * cbuf[j] + iv * gv;
        cbuf[j]  = c;
        float h  = ov * tanhf(c);
        __hip_atomic_store(&h0h[(size_t)(t+1)*1024 + jbase + j], h,
                           __ATOMIC_RELAXED, __HIP_MEMORY_SCOPE_AGENT);
        if (t == T_STEPS - 1) { out_hc[jbase + j] = h; out_hc[2048 + jbase + j] = c; }
      }
      __syncthreads();   // drains vmcnt before barrier -> stores globally visible
      if (tid == 0) {
        __threadfence();
        __hip_atomic_fetch_add(&cnt0[(t+1)*CSTR], 1,
                               __ATOMIC_RELEASE, __HIP_MEMORY_SCOPE_AGENT);
      }
    }
  } else {
    // ---- layer 1: K=2048 concat [h0_t ; h1_{t-1}], 32 w/row/lane -> 256 VGPRs ----
    float wr[8][32];
    const float* wbase = (lane < 32) ? Wih1 : Whh1;
    const int koff = (lane & 31) * 32;
    #pragma unroll
    for (int j = 0; j < 8; ++j) {
      const float* p = wbase + (size_t)(w*1024 + jbase + j) * 1024 + koff;
      #pragma unroll
      for (int q = 0; q < 8; ++q) {
        float4 v = *(const float4*)(p + q*4);
        wr[j][q*4+0]=v.x; wr[j][q*4+1]=v.y; wr[j][q*4+2]=v.z; wr[j][q*4+3]=v.w;
      }
    }
    float bi_i=0.f, bi_f=0.f, bi_g=0.f, bi_o=0.f;
    if (tid < 8) {
      int j = jbase + tid;
      bi_i = bih1[j]        + bhh1[j];
      bi_f = bih1[1024 + j] + bhh1[1024 + j];
      bi_g = bih1[2048 + j] + bhh1[2048 + j];
      bi_o = bih1[3072 + j] + bhh1[3072 + j];
    }
    __syncthreads();
    for (int t = 0; t < T_STEPS; ++t) {
      if (tid == 0) {
        int sp = 0;
        while (__hip_atomic_load(&cnt0[(t+1)*CSTR], __ATOMIC_RELAXED, __HIP_MEMORY_SCOPE_AGENT) < NBLK ||
               __hip_atomic_load(&cnt1[t*CSTR],     __ATOMIC_RELAXED, __HIP_MEMORY_SCOPE_AGENT) < NBLK) {
          __builtin_amdgcn_s_sleep(1);
          if (++sp > SPIN_CAP) break;
        }
      }
      __syncthreads();
      #pragma unroll
      for (int q = 0; q < 8; ++q) {     // waves 0-1 stage h0_t, waves 2-3 stage h1_{t-1}
        int idx = tid*8 + q;
        const float* src = (idx < 1024) ? (h0h + (size_t)(t+1)*1024 + idx)
                                        : (h1h + (size_t)t*1024 + (idx - 1024));
        hbuf[idx] = __hip_atomic_load(const_cast<float*>(src),
                                      __ATOMIC_RELAXED, __HIP_MEMORY_SCOPE_AGENT);
      }
      __syncthreads();
      float acc[8];
      {
        float xv[32];
        const float* hv = &hbuf[lane*32];
        #pragma unroll
        for (int q = 0; q < 8; ++q) {
          float4 v = *(const float4*)(hv + q*4);
          xv[q*4+0]=v.x; xv[q*4+1]=v.y; xv[q*4+2]=v.z; xv[q*4+3]=v.w;
        }
        #pragma unroll
        for (int j = 0; j < 8; ++j) {
          float s = 0.f;
          #pragma unroll
          for (int q = 0; q < 32; ++q) s += wr[j][q] * xv[q];
          acc[j] = s;
        }
      }
      #pragma unroll
      for (int j = 0; j < 8; ++j)
        #pragma unroll
        for (int msk = 1; msk < 64; msk <<= 1)
          acc[j] += __shfl_xor(acc[j], msk, 64);
      if (lane == 0) {
        #pragma unroll
        for (int j = 0; j < 8; ++j) gbuf[w][j] = acc[j];
      }
      __syncthreads();
      if (tid < 8) {
        const int j = tid;
        float iv = sigmoid_f(gbuf[0][j] + bi_i);
        float fv = sigmoid_f(gbuf[1][j] + bi_f);
        float gv = tanhf   (gbuf[2][j] + bi_g);
        float ov = sigmoid_f(gbuf[3][j] + bi_o);
        float c  = fv * cbuf[j] + iv * gv;
        cbuf[j]  = c;
        float h  = ov * tanhf(c);
        __hip_atomic_store(&h1h[(size_t)(t+1)*1024 + jbase + j], h,
                           __ATOMIC_RELAXED, __HIP_MEMORY_SCOPE_AGENT);
        if (t == T_STEPS - 1) { out_hc[1024 + jbase + j] = h; out_hc[2048 + 1024 + jbase + j] = c; }
      }
      __syncthreads();
      if (tid == 0) {
        __threadfence();
        __hip_atomic_fetch_add(&cnt1[(t+1)*CSTR], 1,
                               __ATOMIC_RELEASE, __HIP_MEMORY_SCOPE_AGENT);
      }
    }
  }
}

// ---------------------------------------------------------------------------
extern "C" void kernel_launch(void* const* d_in, const int* in_sizes, int n_in,
                              void* d_out, int out_size, void* d_ws, size_t ws_size,
                              hipStream_t stream)
{
  (void)in_sizes; (void)n_in; (void)out_size; (void)ws_size;
  const int*   x    = (const int*)  d_in[0];
  const float* emb  = (const float*)d_in[1];
  const float* W_ih = (const float*)d_in[2];   // (2, 4096, 1024)
  const float* W_hh = (const float*)d_in[3];
  const float* b_ih = (const float*)d_in[4];   // (2, 4096)
  const float* b_hh = (const float*)d_in[5];
  const float* W_fc = (const float*)d_in[6];   // (32000, 1024)
  const float* b_fc = (const float*)d_in[7];
  float* out = (float*)d_out;                  // scores(512x32000) | h(2x1024) | c(2x1024)

  // workspace layout (floats); ~12.7 MB total
  float* ws   = (float*)d_ws;
  float* G0   = ws;                                        // 512*4096
  float* h0h  = G0  + (size_t)T_STEPS * 4096;              // 513*1024
  float* h1h  = h0h + (size_t)(T_STEPS + 1) * H_DIM;       // 513*1024
  int*   cnt0 = (int*)(h1h + (size_t)(T_STEPS + 1) * H_DIM);
  int*   cnt1 = cnt0 + (T_STEPS + 1) * CSTR;
  int*   xmap = cnt1 + (T_STEPS + 1) * CSTR;               // 512 ints

  init_ws_k<<<32, 256, 0, stream>>>(x, h0h, h1h, cnt0, cnt1, xmap);

  // G0[t,:] = W_ih0 @ emb[x_t] + b_ih0 + b_hh0   (512 x 4096)
  gemm_atb_k<<<dim3(4096 / BN, T_STEPS / BM), 256, 0, stream>>>(
      nullptr, emb, xmap, W_ih, b_ih, b_hh, G0, T_STEPS, 4096, 1024);

  // sequential scan (persistent, both layers pipelined across 256 CUs)
  lstm_seq_k<<<256, 256, 0, stream>>>(
      W_hh, W_ih + (size_t)4096 * 1024, W_hh + (size_t)4096 * 1024,
      b_ih + 4096, b_hh + 4096, G0, h0h, h1h, cnt0, cnt1,
      out + (size_t)T_STEPS * VOCAB);

  // scores = outs @ W_fc^T + b_fc   (outs = h1 history slots 1..512)
  gemm_atb_k<<<dim3(VOCAB / BN, T_STEPS / BM), 256, 0, stream>>>(
      h1h + H_DIM, nullptr, nullptr, W_fc, b_fc, nullptr, out, T_STEPS, VOCAB, 1024);
}

// Round 2
// 4023.569 us; speedup vs baseline: 1.5534x; 1.5534x over previous
//
#include <hip/hip_runtime.h>
#include <cstdint>
#include <cstddef>

// Problem constants
#define H_DIM   1024
#define T_STEPS 512           // L*N = 64*8 flattened time-major
#define VOCAB   32000
#define NBLK    128           // blocks per layer
#define SPIN_CAP 5000000      // hang guard

// ---------------------------------------------------------------------------
// init: zero h slot 0, zero per-step flag arrays, preset slot-0 flags to
// "ready", build time-major gather map xmap[t]=x[n,l].
// flags layout: flagsX[t*128 + b] == 1 when block b of layer X finished step t-1
// (i.e. h slot t is valid).
// ---------------------------------------------------------------------------
__global__ void init_ws_k(const int* __restrict__ x,
                          float* __restrict__ h0h, float* __restrict__ h1h,
                          int* __restrict__ flags0, int* __restrict__ flags1,
                          int* __restrict__ xmap)
{
  int tid = blockIdx.x * blockDim.x + threadIdx.x;
  int nt  = gridDim.x * blockDim.x;
  for (int i = tid; i < H_DIM; i += nt) { h0h[i] = 0.f; h1h[i] = 0.f; }
  for (int i = tid; i < (T_STEPS + 1) * NBLK; i += nt) {
    int v = (i < NBLK) ? 1 : 0;        // slot 0 = initial zero state, ready
    flags0[i] = v; flags1[i] = v;
  }
  for (int t = tid; t < T_STEPS; t += nt) xmap[t] = x[(t & 7) * 64 + (t >> 3)];
}

// ---------------------------------------------------------------------------
// fp32 GEMM  C[M,N] = A[M,K] @ B[N,K]^T + bias0 + bias1.
// If A==null, row t of A is gathered as emb[xmap[t]].
// 128x128 tile, BK=16, 256 threads, 8x8 per-thread microtile.
// ---------------------------------------------------------------------------
#define BM 128
#define BN 128
#define BKD 16

__global__ __launch_bounds__(256) void gemm_atb_k(
    const float* __restrict__ A, const float* __restrict__ emb,
    const int* __restrict__ xmap,
    const float* __restrict__ B,
    const float* __restrict__ bias0, const float* __restrict__ bias1,
    float* __restrict__ C, int M, int N, int K)
{
  __shared__ __align__(16) float As[BKD][BM + 4];
  __shared__ __align__(16) float Bs[BKD][BN + 4];
  const int tid = threadIdx.x;
  const int tx = tid & 15, ty = tid >> 4;
  const int m0 = blockIdx.y * BM, n0 = blockIdx.x * BN;
  const int lr = tid >> 1;           // 0..127: row within tile
  const int lk = (tid & 1) * 8;      // 0 or 8: k sub-chunk
  const float* arow = A ? (A + (size_t)(m0 + lr) * K)
                        : (emb + (size_t)xmap[m0 + lr] * K);
  const float* brow = B + (size_t)(n0 + lr) * K;

  float acc[8][8];
  #pragma unroll
  for (int i = 0; i < 8; ++i)
    #pragma unroll
    for (int j = 0; j < 8; ++j) acc[i][j] = 0.f;

  for (int k0 = 0; k0 < K; k0 += BKD) {
    float4 a0 = *(const float4*)(arow + k0 + lk);
    float4 a1 = *(const float4*)(arow + k0 + lk + 4);
    float4 b0 = *(const float4*)(brow + k0 + lk);
    float4 b1 = *(const float4*)(brow + k0 + lk + 4);
    __syncthreads();   // protect previous iteration's LDS reads
    As[lk+0][lr]=a0.x; As[lk+1][lr]=a0.y; As[lk+2][lr]=a0.z; As[lk+3][lr]=a0.w;
    As[lk+4][lr]=a1.x; As[lk+5][lr]=a1.y; As[lk+6][lr]=a1.z; As[lk+7][lr]=a1.w;
    Bs[lk+0][lr]=b0.x; Bs[lk+1][lr]=b0.y; Bs[lk+2][lr]=b0.z; Bs[lk+3][lr]=b0.w;
    Bs[lk+4][lr]=b1.x; Bs[lk+5][lr]=b1.y; Bs[lk+6][lr]=b1.z; Bs[lk+7][lr]=b1.w;
    __syncthreads();
    #pragma unroll
    for (int kk = 0; kk < BKD; ++kk) {
      float4 av0 = *(const float4*)&As[kk][ty*8];
      float4 av1 = *(const float4*)&As[kk][ty*8+4];
      float4 bv0 = *(const float4*)&Bs[kk][tx*8];
      float4 bv1 = *(const float4*)&Bs[kk][tx*8+4];
      float av[8] = {av0.x,av0.y,av0.z,av0.w,av1.x,av1.y,av1.z,av1.w};
      float bv[8] = {bv0.x,bv0.y,bv0.z,bv0.w,bv1.x,bv1.y,bv1.z,bv1.w};
      #pragma unroll
      for (int i = 0; i < 8; ++i)
        #pragma unroll
        for (int j = 0; j < 8; ++j) acc[i][j] += av[i] * bv[j];
    }
  }
  float bvp[8];
  #pragma unroll
  for (int j = 0; j < 8; ++j) {
    int n = n0 + tx*8 + j;
    float s = 0.f;
    if (bias0) s += bias0[n];
    if (bias1) s += bias1[n];
    bvp[j] = s;
  }
  #pragma unroll
  for (int i = 0; i < 8; ++i) {
    int m = m0 + ty*8 + i;
    float* crow = C + (size_t)m * N + n0 + tx*8;
    float4 o0, o1;
    o0.x=acc[i][0]+bvp[0]; o0.y=acc[i][1]+bvp[1]; o0.z=acc[i][2]+bvp[2]; o0.w=acc[i][3]+bvp[3];
    o1.x=acc[i][4]+bvp[4]; o1.y=acc[i][5]+bvp[5]; o1.z=acc[i][6]+bvp[6]; o1.w=acc[i][7]+bvp[7];
    *(float4*)crow = o0;
    *(float4*)(crow + 4) = o1;
  }
}

// ---------------------------------------------------------------------------
// Persistent sequential LSTM scan. 256 blocks x 256 threads, 1 block/CU.
// Blocks 0..127: layer 0 (W_hh0 in regs; W_ih0 path precomputed into G0).
// Blocks 128..255: layer 1 ([W_ih1|W_hh1] in regs, K=2048), lags one step.
// Block b owns hidden units j in [8b, 8b+8) for all 4 gates + their c state.
//
// Sync: per-(step,block) FLAG WORDS, plain write-through stores (no RMW —
// round 1 showed 128 atomic-adds/step to one word serialize at the coherence
// point, ~20K cycles/step). Ordering: __syncthreads() drains vmcnt(0) per
// wave (m97 asm evidence), so the sc1 h-stores are at the coherence point
// before the flag store issues. Consumers read h with sc1 (cache-bypassing)
// loads, so flag-visible => h-visible.
//
// LDS layout: lane reads k = q*256 + lane*4 (ds_read_b128 perfectly striped,
// conflict-free; round 1 had 1.07e8 conflict cycles from 64B lane stride).
// Register weight layout permuted to match; global weight loads stay coalesced.
// ---------------------------------------------------------------------------
__device__ __forceinline__ float sigmoid_f(float v) { return 1.f / (1.f + expf(-v)); }

__global__ __launch_bounds__(256, 1) void lstm_seq_k(
    const float* __restrict__ Whh0,
    const float* __restrict__ Wih1,
    const float* __restrict__ Whh1,
    const float* __restrict__ bih1,
    const float* __restrict__ bhh1,
    const float* __restrict__ G0,
    float* __restrict__ h0h, float* __restrict__ h1h,   // (T+1) x 1024 histories
    int* __restrict__ flags0, int* __restrict__ flags1,
    float* __restrict__ out_hc)                          // h(2x1024) then c(2x1024)
{
  const int Bid   = blockIdx.x;
  const int layer = Bid >> 7;
  const int b     = Bid & 127;
  const int jbase = b * 8;
  const int tid   = threadIdx.x;
  const int w     = tid >> 6;    // wave index == gate index (i,f,g,o)
  const int lane  = tid & 63;    // k-chunk index

  __shared__ __align__(16) float hbuf[2048];
  __shared__ float gbuf[4][8];
  __shared__ float cbuf[8];

  if (tid < 8) cbuf[tid] = 0.f;

  if (layer == 0) {
    // ---- layer 0: K=1024. Lane holds k = q*256 + lane*4 + r, q<4, r<4 ----
    float wr[8][16];
    #pragma unroll
    for (int j = 0; j < 8; ++j) {
      const float* p = Whh0 + (size_t)(w*1024 + jbase + j) * 1024 + lane*4;
      #pragma unroll
      for (int q = 0; q < 4; ++q) {
        float4 v = *(const float4*)(p + q*256);
        wr[j][q*4+0]=v.x; wr[j][q*4+1]=v.y; wr[j][q*4+2]=v.z; wr[j][q*4+3]=v.w;
      }
    }
    __syncthreads();
    for (int t = 0; t < T_STEPS; ++t) {
      if (tid < 64) {                      // wave 0 polls all 128 producer flags
        const int* f = flags0 + t * NBLK;
        int sp = 0;
        for (;;) {
          int a = __hip_atomic_load(&f[tid],      __ATOMIC_RELAXED, __HIP_MEMORY_SCOPE_AGENT);
          int c2 = __hip_atomic_load(&f[tid + 64], __ATOMIC_RELAXED, __HIP_MEMORY_SCOPE_AGENT);
          if (__all(a && c2)) break;
          __builtin_amdgcn_s_sleep(1);
          if (++sp > SPIN_CAP) break;
        }
      }
      __syncthreads();
      // issue G0 loads early so their latency hides under the matvec
      float g_i = 0.f, g_f = 0.f, g_g = 0.f, g_o = 0.f;
      if (tid < 8) {
        const float* g0 = G0 + (size_t)t*4096 + jbase + tid;
        g_i = g0[0]; g_f = g0[1024]; g_g = g0[2048]; g_o = g0[3072];
      }
      { // stage h_{t-1}: coalesced sc1 loads, stride-1 LDS writes
        const float* src = h0h + (size_t)t * 1024;
        #pragma unroll
        for (int q = 0; q < 4; ++q) {
          int idx = q*256 + tid;
          hbuf[idx] = __hip_atomic_load(const_cast<float*>(&src[idx]),
                                        __ATOMIC_RELAXED, __HIP_MEMORY_SCOPE_AGENT);
        }
      }
      __syncthreads();
      float acc[8];
      {
        float xv[16];
        #pragma unroll
        for (int q = 0; q < 4; ++q) {
          float4 v = *(const float4*)&hbuf[q*256 + lane*4];
          xv[q*4+0]=v.x; xv[q*4+1]=v.y; xv[q*4+2]=v.z; xv[q*4+3]=v.w;
        }
        #pragma unroll
        for (int j = 0; j < 8; ++j) {
          float s = 0.f;
          #pragma unroll
          for (int q = 0; q < 16; ++q) s += wr[j][q] * xv[q];
          acc[j] = s;
        }
      }
      #pragma unroll
      for (int j = 0; j < 8; ++j)
        #pragma unroll
        for (int msk = 1; msk < 64; msk <<= 1)
          acc[j] += __shfl_xor(acc[j], msk, 64);
      if (lane == 0) {
        #pragma unroll
        for (int j = 0; j < 8; ++j) gbuf[w][j] = acc[j];
      }
      __syncthreads();
      if (tid < 8) {
        const int j = tid;
        float iv = sigmoid_f(gbuf[0][j] + g_i);
        float fv = sigmoid_f(gbuf[1][j] + g_f);
        float gv = tanhf   (gbuf[2][j] + g_g);
        float ov = sigmoid_f(gbuf[3][j] + g_o);
        float c  = fv * cbuf[j] + iv * gv;
        cbuf[j]  = c;
        float h  = ov * tanhf(c);
        __hip_atomic_store(&h0h[(size_t)(t+1)*1024 + jbase + j], h,
                           __ATOMIC_RELAXED, __HIP_MEMORY_SCOPE_AGENT);
        if (t == T_STEPS - 1) { out_hc[jbase + j] = h; out_hc[2048 + jbase + j] = c; }
      }
      __syncthreads();   // drains vmcnt(0) per wave -> h stores at coherence point
      if (tid == 0)
        __hip_atomic_store(&flags0[(t+1)*NBLK + b], 1,
                           __ATOMIC_RELAXED, __HIP_MEMORY_SCOPE_AGENT);
    }
  } else {
    // ---- layer 1: K=2048 concat [h0_t ; h1_{t-1}], k = q*256 + lane*4 + r ----
    float wr[8][32];
    #pragma unroll
    for (int j = 0; j < 8; ++j) {
      #pragma unroll
      for (int q = 0; q < 8; ++q) {
        const float* base = (q < 4) ? Wih1 : Whh1;
        const float* p = base + (size_t)(w*1024 + jbase + j) * 1024 + (q & 3)*256 + lane*4;
        float4 v = *(const float4*)p;
        wr[j][q*4+0]=v.x; wr[j][q*4+1]=v.y; wr[j][q*4+2]=v.z; wr[j][q*4+3]=v.w;
      }
    }
    float bi_i=0.f, bi_f=0.f, bi_g=0.f, bi_o=0.f;
    if (tid < 8) {
      int j = jbase + tid;
      bi_i = bih1[j]        + bhh1[j];
      bi_f = bih1[1024 + j] + bhh1[1024 + j];
      bi_g = bih1[2048 + j] + bhh1[2048 + j];
      bi_o = bih1[3072 + j] + bhh1[3072 + j];
    }
    __syncthreads();
    for (int t = 0; t < T_STEPS; ++t) {
      if (tid < 64) {                      // poll layer0 step t+1 AND layer1 step t
        const int* fa = flags0 + (t+1) * NBLK;
        const int* fb = flags1 + t * NBLK;
        int sp = 0;
        for (;;) {
          int a0 = __hip_atomic_load(&fa[tid],      __ATOMIC_RELAXED, __HIP_MEMORY_SCOPE_AGENT);
          int a1 = __hip_atomic_load(&fa[tid + 64], __ATOMIC_RELAXED, __HIP_MEMORY_SCOPE_AGENT);
          int b0 = __hip_atomic_load(&fb[tid],      __ATOMIC_RELAXED, __HIP_MEMORY_SCOPE_AGENT);
          int b1 = __hip_atomic_load(&fb[tid + 64], __ATOMIC_RELAXED, __HIP_MEMORY_SCOPE_AGENT);
          if (__all(a0 && a1 && b0 && b1)) break;
          __builtin_amdgcn_s_sleep(1);
          if (++sp > SPIN_CAP) break;
        }
      }
      __syncthreads();
      { // stage concat [h0_{t+1} ; h1_t]: coalesced, stride-1 LDS writes
        const float* s0 = h0h + (size_t)(t+1) * 1024;
        const float* s1 = h1h + (size_t)t * 1024;
        #pragma unroll
        for (int q = 0; q < 8; ++q) {
          int idx = q*256 + tid;
          const float* src = (q < 4) ? (s0 + idx) : (s1 + idx - 1024);
          hbuf[idx] = __hip_atomic_load(const_cast<float*>(src),
                                        __ATOMIC_RELAXED, __HIP_MEMORY_SCOPE_AGENT);
        }
      }
      __syncthreads();
      float acc[8];
      {
        float xv[32];
        #pragma unroll
        for (int q = 0; q < 8; ++q) {
          float4 v = *(const float4*)&hbuf[q*256 + lane*4];
          xv[q*4+0]=v.x; xv[q*4+1]=v.y; xv[q*4+2]=v.z; xv[q*4+3]=v.w;
        }
        #pragma unroll
        for (int j = 0; j < 8; ++j) {
          float s = 0.f;
          #pragma unroll
          for (int q = 0; q < 32; ++q) s += wr[j][q] * xv[q];
          acc[j] = s;
        }
      }
      #pragma unroll
      for (int j = 0; j < 8; ++j)
        #pragma unroll
        for (int msk = 1; msk < 64; msk <<= 1)
          acc[j] += __shfl_xor(acc[j], msk, 64);
      if (lane == 0) {
        #pragma unroll
        for (int j = 0; j < 8; ++j) gbuf[w][j] = acc[j];
      }
      __syncthreads();
      if (tid < 8) {
        const int j = tid;
        float iv = sigmoid_f(gbuf[0][j] + bi_i);
        float fv = sigmoid_f(gbuf[1][j] + bi_f);
        float gv = tanhf   (gbuf[2][j] + bi_g);
        float ov = sigmoid_f(gbuf[3][j] + bi_o);
        float c  = fv * cbuf[j] + iv * gv;
        cbuf[j]  = c;
        float h  = ov * tanhf(c);
        __hip_atomic_store(&h1h[(size_t)(t+1)*1024 + jbase + j], h,
                           __ATOMIC_RELAXED, __HIP_MEMORY_SCOPE_AGENT);
        if (t == T_STEPS - 1) { out_hc[1024 + jbase + j] = h; out_hc[2048 + 1024 + jbase + j] = c; }
      }
      __syncthreads();
      if (tid == 0)
        __hip_atomic_store(&flags1[(t+1)*NBLK + b], 1,
                           __ATOMIC_RELAXED, __HIP_MEMORY_SCOPE_AGENT);
    }
  }
}

// ---------------------------------------------------------------------------
extern "C" void kernel_launch(void* const* d_in, const int* in_sizes, int n_in,
                              void* d_out, int out_size, void* d_ws, size_t ws_size,
                              hipStream_t stream)
{
  (void)in_sizes; (void)n_in; (void)out_size; (void)ws_size;
  const int*   x    = (const int*)  d_in[0];
  const float* emb  = (const float*)d_in[1];
  const float* W_ih = (const float*)d_in[2];   // (2, 4096, 1024)
  const float* W_hh = (const float*)d_in[3];
  const float* b_ih = (const float*)d_in[4];   // (2, 4096)
  const float* b_hh = (const float*)d_in[5];
  const float* W_fc = (const float*)d_in[6];   // (32000, 1024)
  const float* b_fc = (const float*)d_in[7];
  float* out = (float*)d_out;                  // scores(512x32000) | h(2x1024) | c(2x1024)

  // workspace layout (floats); ~13 MB total
  float* ws     = (float*)d_ws;
  float* G0     = ws;                                        // 512*4096
  float* h0h    = G0  + (size_t)T_STEPS * 4096;              // 513*1024
  float* h1h    = h0h + (size_t)(T_STEPS + 1) * H_DIM;       // 513*1024
  int*   flags0 = (int*)(h1h + (size_t)(T_STEPS + 1) * H_DIM);
  int*   flags1 = flags0 + (T_STEPS + 1) * NBLK;
  int*   xmap   = flags1 + (T_STEPS + 1) * NBLK;             // 512 ints

  init_ws_k<<<64, 256, 0, stream>>>(x, h0h, h1h, flags0, flags1, xmap);

  // G0[t,:] = W_ih0 @ emb[x_t] + b_ih0 + b_hh0   (512 x 4096)
  gemm_atb_k<<<dim3(4096 / BN, T_STEPS / BM), 256, 0, stream>>>(
      nullptr, emb, xmap, W_ih, b_ih, b_hh, G0, T_STEPS, 4096, 1024);

  // sequential scan (persistent, both layers pipelined across 256 CUs)
  lstm_seq_k<<<256, 256, 0, stream>>>(
      W_hh, W_ih + (size_t)4096 * 1024, W_hh + (size_t)4096 * 1024,
      b_ih + 4096, b_hh + 4096, G0, h0h, h1h, flags0, flags1,
      out + (size_t)T_STEPS * VOCAB);

  // scores = outs @ W_fc^T + b_fc   (outs = h1 history slots 1..512)
  gemm_atb_k<<<dim3(VOCAB / BN, T_STEPS / BM), 256, 0, stream>>>(
      h1h + H_DIM, nullptr, nullptr, W_fc, b_fc, nullptr, out, T_STEPS, VOCAB, 1024);
}